// Round 9
// baseline (244.076 us; speedup 1.0000x reference)
//
#include <hip/hip_runtime.h>
#include <math.h>

#define G 64
#define NDIM 512
#define FIN 7
#define HID 64
#define CLS 2
#define KPOOL 128

typedef unsigned long long u64;

__device__ __forceinline__ float wred64(float v){
  #pragma unroll
  for (int o = 32; o > 0; o >>= 1) v += __shfl_xor(v, o, 64);
  return v;
}

// ---- build transposed bitmasks: maskT[g][u][i] bit l = adj[g][i][u*64+l] ---
__global__ __launch_bounds__(256) void mask_kernel(const float* __restrict__ adj,
                                                   u64* __restrict__ maskT){
  const int wid = threadIdx.x >> 6, lane = threadIdx.x & 63;
  const int row = blockIdx.x * 4 + wid;          // [0, G*NDIM)
  const int g = row >> 9, i = row & 511;
  const float* ar = adj + (size_t)row * NDIM;
  u64 b[8];
  #pragma unroll
  for (int u = 0; u < 8; u++)
    b[u] = __ballot(ar[u * 64 + lane] != 0.0f);
  if (lane == 0){
    u64* mt = maskT + (size_t)g * 8 * NDIM + i;
    #pragma unroll
    for (int u = 0; u < 8; u++) mt[(size_t)u * NDIM] = b[u];
  }
}

// ---- A2 = adj@adj via popcount(m_i & m_k), output u8 (entries <= ~60) -----
__global__ __launch_bounds__(256) void a2_kernel(const u64* __restrict__ maskT,
                                                 unsigned char* __restrict__ A2u8){
  const int bid = blockIdx.x;
  const int g = (bid & 7) + 8 * ((bid >> 3) & 7);
  const int chunk = bid >> 6;                    // [0,8): rows [chunk*64, +64)
  const int tid = threadIdx.x, wid = tid >> 6, lane = tid & 63;
  __shared__ u64 mt[8][NDIM];                    // 32 KB: whole graph's masks
  {
    const uint4* s4 = (const uint4*)(maskT + (size_t)g * 8 * NDIM);
    uint4* d4 = (uint4*)&mt[0][0];
    #pragma unroll
    for (int s = 0; s < 8; s++) d4[tid + 256 * s] = s4[tid + 256 * s];
  }
  __syncthreads();
  #pragma unroll 1
  for (int rr = 0; rr < 16; rr++){
    const int i = chunk * 64 + wid * 16 + rr;
    u64 mi[8];
    #pragma unroll
    for (int u = 0; u < 8; u++) mi[u] = mt[u][i];
    unsigned char* orow = A2u8 + ((size_t)g * NDIM + i) * NDIM;
    #pragma unroll
    for (int q = 0; q < 8; q++){
      int c = 0;
      #pragma unroll
      for (int u = 0; u < 8; u++)
        c += __popcll(mt[u][q * 64 + lane] & mi[u]);
      orow[q * 64 + lane] = (unsigned char)c;
    }
  }
}

// ---- sparse apply helpers (per-lane mask iteration) -----------------------
__device__ __forceinline__ float apply1(const u64* mi, const float* src){
  float a = 0.f;
  #pragma unroll
  for (int u = 0; u < 8; u++){
    u64 mm = mi[u];
    while (mm){ int l = __builtin_ctzll(mm); mm &= mm - 1; a += src[u * 64 + l]; }
  }
  return a;
}

__device__ __forceinline__ void apply7(const u64* mi, const float (*src)[NDIM],
                                       float* dst){
  #pragma unroll
  for (int f = 0; f < FIN; f++) dst[f] = 0.f;
  #pragma unroll
  for (int u = 0; u < 8; u++){
    u64 mm = mi[u];
    while (mm){
      int l = __builtin_ctzll(mm); mm &= mm - 1;
      int k = u * 64 + l;
      #pragma unroll
      for (int f = 0; f < FIN; f++) dst[f] += src[f][k];
    }
  }
}

// ---- fused per-graph: deg chain, d, s2, h (in regs), score, top-k, xp -----
// thread t = node t. M*v applied as c0 v + c1 Av + c2 A^2 v + c3 A^3 v.
__global__ __launch_bounds__(512) void score_kernel(
    const u64* __restrict__ maskT, const float* __restrict__ x,
    const float* __restrict__ panw, const float* __restrict__ w1,
    const float* __restrict__ b1, const float* __restrict__ pvec,
    const float* __restrict__ beta,
    float* __restrict__ dvec, int* __restrict__ idxOut,
    float* __restrict__ valOut, float* __restrict__ xp)
{
  const int g = blockIdx.x, t = threadIdx.x;     // t in [0,512)
  __shared__ float sA[NDIM], sB[NDIM], dl[NDIM], sv[NDIM];
  __shared__ float z[FIN][NDIM], zb[FIN][NDIM];
  __shared__ float W1s[FIN * HID];
  __shared__ float ps[HID];

  u64 mi[8];
  {
    const u64* mrow = maskT + (size_t)g * 8 * NDIM + t;
    #pragma unroll
    for (int u = 0; u < 8; u++) mi[u] = mrow[(size_t)u * NDIM];
  }
  if (t < FIN * HID) W1s[t] = w1[t];
  if (t < HID) ps[t] = pvec[t];

  const float w0 = panw[0], ww1 = panw[1], ww2 = panw[2], ww3 = panw[3];
  const float c0 = w0, c1 = c0 * ww1, c2 = c1 * ww2, c3 = c2 * ww3;

  // deg chain: d1 = A·1, d2 = A·d1, d3 = A·d2 (exact integers)
  int cdeg = 0;
  #pragma unroll
  for (int u = 0; u < 8; u++) cdeg += (int)__popcll(mi[u]);
  const float d1 = (float)cdeg;
  sA[t] = d1;
  __syncthreads();
  const float d2 = apply1(mi, sA);
  sB[t] = d2;
  __syncthreads();
  const float d3 = apply1(mi, sB);
  const float rs = c0 + c1 * d1 + c2 * d2 + c3 * d3;
  const float dd = rsqrtf(fmaxf(rs, 1.0f));
  dl[t] = dd;
  dvec[g * NDIM + t] = dd;
  __syncthreads();
  // s2 = d ∘ (M d)
  const float e1 = apply1(mi, dl);
  __syncthreads();
  sA[t] = e1;
  __syncthreads();
  const float e2 = apply1(mi, sA);
  __syncthreads();
  sB[t] = e2;
  __syncthreads();
  const float e3 = apply1(mi, sB);
  const float s2v = dd * (c0 * dd + c1 * e1 + c2 * e2 + c3 * e3);

  // z = d ∘ x ; y = c0 z + c1 Az + c2 A²z + c3 A³z
  float y[FIN];
  #pragma unroll
  for (int f = 0; f < FIN; f++){
    float zv = dd * x[((size_t)g * NDIM + t) * FIN + f];
    z[f][t] = zv;
    y[f] = c0 * zv;
  }
  __syncthreads();
  float w[FIN];
  apply7(mi, z, w);
  #pragma unroll
  for (int f = 0; f < FIN; f++){ y[f] += c1 * w[f]; zb[f][t] = w[f]; }
  __syncthreads();
  apply7(mi, zb, w);
  #pragma unroll
  for (int f = 0; f < FIN; f++) y[f] += c2 * w[f];
  __syncthreads();                     // all zb reads done; safe to reuse z
  #pragma unroll
  for (int f = 0; f < FIN; f++) z[f][t] = w[f];
  __syncthreads();
  apply7(mi, z, w);
  #pragma unroll
  for (int f = 0; f < FIN; f++) y[f] += c3 * w[f];

  // h row in registers; s1 = <h, p>
  float yin[FIN];
  #pragma unroll
  for (int f = 0; f < FIN; f++) yin[f] = dd * y[f];
  float hv[HID];
  float s1 = 0.f;
  #pragma unroll
  for (int o = 0; o < HID; o++){
    float zz = b1[o];
    #pragma unroll
    for (int f = 0; f < FIN; f++) zz = fmaf(yin[f], W1s[f * HID + o], zz);
    hv[o] = fmaxf(zz, 0.f);
    s1 = fmaf(hv[o], ps[o], s1);
  }
  const float sc = tanhf(beta[0] * s1 + beta[1] * s2v);
  sv[t] = sc;
  __syncthreads();
  // rank selection (val desc, idx asc) — proven round-6 logic
  int rank = 0;
  #pragma unroll 8
  for (int j = 0; j < NDIM; j++){
    float u_ = sv[j];
    rank += (u_ > sc || (u_ == sc && j < t)) ? 1 : 0;
  }
  if (rank < KPOOL){
    idxOut[g * KPOOL + rank] = t;
    valOut[g * KPOOL + rank] = sc;
    float* xr = xp + ((size_t)g * KPOOL + rank) * HID;
    #pragma unroll
    for (int o = 0; o < HID; o++) xr[o] = hv[o] * sc;
  }
}

// ---- pooled adjacency from masks + A2u8: Apool = Mn[idx,idx] + I, di ------
// B2[k][c] = A2[k][idx[c]] staged in LDS per 256-row half; A3pool row r =
// sum over k in N(idx[r]) of B2[k][c]. Same fmaf epilogue as old m-path.
__global__ __launch_bounds__(512) void pool_kernel(
    const u64* __restrict__ maskT, const unsigned char* __restrict__ A2u8,
    const int* __restrict__ idx, const float* __restrict__ dvec,
    const float* __restrict__ panw,
    float* __restrict__ Apool, float* __restrict__ di)
{
  const int g = blockIdx.x;
  const int tid = threadIdx.x;                   // 512
  const int grp = tid >> 7;                      // 0..3 (row group)
  const int c = tid & 127;                       // pooled column
  __shared__ unsigned char B2[256][128];         // 32 KB
  __shared__ int idxs[KPOOL];
  __shared__ float dp[KPOOL];
  __shared__ u64 mp[KPOOL][8];                   // 8 KB
  __shared__ float part[4][2];

  if (tid < KPOOL){
    int ia = idx[g * KPOOL + tid];
    idxs[tid] = ia;
    dp[tid] = dvec[g * NDIM + ia];
  }
  __syncthreads();
  for (int q = tid; q < KPOOL * 8; q += 512){
    int r = q >> 3, u = q & 7;
    mp[r][u] = maskT[(size_t)g * 8 * NDIM + (size_t)u * NDIM + idxs[r]];
  }
  const unsigned char* A2g = A2u8 + (size_t)g * NDIM * NDIM;

  float a3acc[32];
  #pragma unroll
  for (int rr = 0; rr < 32; rr++) a3acc[rr] = 0.f;

  #pragma unroll 1
  for (int half = 0; half < 2; half++){
    __syncthreads();
    for (int q = tid; q < 256 * 128; q += 512){
      int k = q >> 7, cc = q & 127;
      B2[k][cc] = A2g[(size_t)(half * 256 + k) * NDIM + idxs[cc]];
    }
    __syncthreads();
    #pragma unroll
    for (int rr = 0; rr < 32; rr++){
      const int r = grp * 32 + rr;
      float a = a3acc[rr];
      #pragma unroll
      for (int u = 0; u < 4; u++){
        u64 mm = mp[r][half * 4 + u];
        while (mm){
          int l = __builtin_ctzll(mm); mm &= mm - 1;
          a += (float)B2[u * 64 + l][c];
        }
      }
      a3acc[rr] = a;
    }
  }

  const float w0 = panw[0], ww1 = panw[1], ww2 = panw[2], ww3 = panw[3];
  const float c0 = w0, c1 = c0 * ww1, c2 = c1 * ww2, c3 = c2 * ww3;
  const int ic = idxs[c];
  const float dpc = dp[c];
  #pragma unroll
  for (int rr = 0; rr < 32; rr++){
    const int r = grp * 32 + rr;
    const int ir = idxs[r];
    float a2own = (float)A2g[(size_t)ir * NDIM + ic];
    float ab = (float)((mp[r][ic >> 6] >> (ic & 63)) & 1ull);
    float m = fmaf(c3, a3acc[rr], fmaf(c2, a2own, c1 * ab));
    if (r == c) m += c0;
    float v = m * dp[r] * dpc;
    if (r == c) v += 1.0f;
    Apool[((size_t)g * KPOOL + r) * KPOOL + c] = v;
    float s = wred64(v);
    if ((tid & 63) == 0) part[grp][(tid >> 6) & 1] = s;
    __syncthreads();
    if (c == 0){
      float dgs = part[grp][0] + part[grp][1];
      di[g * KPOOL + r] = dgs > 0.f ? rsqrtf(dgs) : 0.f;
    }
    __syncthreads();
  }
}

// ---------------- pooled GCN: h2 = relu((An xp) W + b) ---------------------
__global__ __launch_bounds__(256) void gcn_kernel(
    const float* __restrict__ Apool, const float* __restrict__ di,
    const float* __restrict__ xp, const float* __restrict__ gw,
    const float* __restrict__ gb, float* __restrict__ h2)
{
  const int wid = threadIdx.x >> 6, lane = threadIdx.x & 63;
  const int row = blockIdx.x * 4 + wid;
  const int g = row >> 7, r = row & 127;
  const float dir = di[g * KPOOL + r];
  float acc = 0.f;
  for (int b = 0; b < KPOOL; b++){
    float an = Apool[(size_t)row * KPOOL + b] * dir * di[g * KPOOL + b];
    acc = fmaf(an, xp[((size_t)g * KPOOL + b) * HID + lane], acc);
  }
  __shared__ float ts[4][HID];
  ts[wid][lane] = acc;
  __syncthreads();
  float z = gb[lane];
  for (int f = 0; f < HID; f++) z = fmaf(ts[wid][f], gw[f * HID + lane], z);
  h2[(size_t)row * HID + lane] = fmaxf(z, 0.f);
}

// ---------------- head: pooled sum + linear + log_softmax ------------------
__global__ void head_kernel(const float* __restrict__ h2,
                            const float* __restrict__ lw,
                            const float* __restrict__ lb,
                            float* __restrict__ out)
{
  const int g = blockIdx.x;
  const int lane = threadIdx.x;
  float p = 0.f;
  for (int k = 0; k < KPOOL; k++) p += h2[((size_t)g * KPOOL + k) * HID + lane];
  float z0 = p * lw[lane * CLS + 0];
  float z1 = p * lw[lane * CLS + 1];
  z0 = wred64(z0);
  z1 = wred64(z1);
  if (lane == 0){
    float l0 = z0 + lb[0], l1 = z1 + lb[1];
    float m = fmaxf(l0, l1);
    float lse = m + logf(expf(l0 - m) + expf(l1 - m));
    out[g * CLS + 0] = l0 - lse;
    out[g * CLS + 1] = l1 - lse;
  }
}

extern "C" void kernel_launch(void* const* d_in, const int* in_sizes, int n_in,
                              void* d_out, int out_size, void* d_ws, size_t ws_size,
                              hipStream_t stream)
{
  const float* x    = (const float*)d_in[0];
  const float* adj  = (const float*)d_in[1];
  const float* panw = (const float*)d_in[2];
  const float* w1   = (const float*)d_in[3];
  const float* b1   = (const float*)d_in[4];
  const float* pvec = (const float*)d_in[5];
  const float* beta = (const float*)d_in[6];
  const float* gw   = (const float*)d_in[7];
  const float* gbv  = (const float*)d_in[8];
  const float* lw   = (const float*)d_in[9];
  const float* lb   = (const float*)d_in[10];
  float* out = (float*)d_out;

  char* ws = (char*)d_ws;
  u64* maskT = (u64*)ws;                                    // 2 MB
  unsigned char* A2u8 = (unsigned char*)(ws + (1 << 21));   // 16.8 MB
  char* p = ws + (1 << 21) + 16777216;
  float* dvec  = (float*)p;                       p += (size_t)G * NDIM * 4;
  int*   idx   = (int*)p;                         p += (size_t)G * KPOOL * 4;
  float* vals  = (float*)p;                       p += (size_t)G * KPOOL * 4;
  float* di    = (float*)p;                       p += (size_t)G * KPOOL * 4;
  float* xp    = (float*)p;                       p += (size_t)G * KPOOL * HID * 4;
  float* Apool = (float*)p;                       p += (size_t)G * KPOOL * KPOOL * 4;
  float* h2    = (float*)p;

  mask_kernel<<<G * NDIM / 4, 256, 0, stream>>>(adj, maskT);
  a2_kernel<<<512, 256, 0, stream>>>(maskT, A2u8);
  score_kernel<<<G, 512, 0, stream>>>(maskT, x, panw, w1, b1, pvec, beta,
                                      dvec, idx, vals, xp);
  pool_kernel<<<G, 512, 0, stream>>>(maskT, A2u8, idx, dvec, panw, Apool, di);
  gcn_kernel<<<G * KPOOL / 4, 256, 0, stream>>>(Apool, di, xp, gw, gbv, h2);
  head_kernel<<<G, 64, 0, stream>>>(h2, lw, lb, out);
}

// Round 10
// 167.649 us; speedup vs baseline: 1.4559x; 1.4559x over previous
//
#include <hip/hip_runtime.h>
#include <math.h>

#define G 64
#define NDIM 512
#define FIN 7
#define HID 64
#define CLS 2
#define KPOOL 128

typedef unsigned long long u64;

__device__ __forceinline__ float wred64(float v){
  #pragma unroll
  for (int o = 32; o > 0; o >>= 1) v += __shfl_xor(v, o, 64);
  return v;
}

// ---- build transposed bitmasks: maskT[g][u][i] bit l = adj[g][i][u*64+l] ---
__global__ __launch_bounds__(256) void mask_kernel(const float* __restrict__ adj,
                                                   u64* __restrict__ maskT){
  const int wid = threadIdx.x >> 6, lane = threadIdx.x & 63;
  const int row = blockIdx.x * 4 + wid;          // [0, G*NDIM)
  const int g = row >> 9, i = row & 511;
  const float* ar = adj + (size_t)row * NDIM;
  u64 b[8];
  #pragma unroll
  for (int u = 0; u < 8; u++)
    b[u] = __ballot(ar[u * 64 + lane] != 0.0f);
  if (lane == 0){
    u64* mt = maskT + (size_t)g * 8 * NDIM + i;
    #pragma unroll
    for (int u = 0; u < 8; u++) mt[(size_t)u * NDIM] = b[u];
  }
}

// ---- A2 = adj@adj via popcount(m_i & m_k), output u8 (entries <= ~60) -----
__global__ __launch_bounds__(256) void a2_kernel(const u64* __restrict__ maskT,
                                                 unsigned char* __restrict__ A2u8){
  const int bid = blockIdx.x;
  const int g = (bid & 7) + 8 * ((bid >> 3) & 7);
  const int chunk = bid >> 6;                    // [0,8): rows [chunk*64, +64)
  const int tid = threadIdx.x, wid = tid >> 6, lane = tid & 63;
  __shared__ u64 mt[8][NDIM];                    // 32 KB: whole graph's masks
  {
    const uint4* s4 = (const uint4*)(maskT + (size_t)g * 8 * NDIM);
    uint4* d4 = (uint4*)&mt[0][0];
    #pragma unroll
    for (int s = 0; s < 8; s++) d4[tid + 256 * s] = s4[tid + 256 * s];
  }
  __syncthreads();
  #pragma unroll 1
  for (int rr = 0; rr < 16; rr++){
    const int i = chunk * 64 + wid * 16 + rr;
    u64 mi[8];
    #pragma unroll
    for (int u = 0; u < 8; u++) mi[u] = mt[u][i];
    unsigned char* orow = A2u8 + ((size_t)g * NDIM + i) * NDIM;
    #pragma unroll
    for (int q = 0; q < 8; q++){
      int c = 0;
      #pragma unroll
      for (int u = 0; u < 8; u++)
        c += __popcll(mt[u][q * 64 + lane] & mi[u]);
      orow[q * 64 + lane] = (unsigned char)c;
    }
  }
}

// ---- sparse apply helpers (per-lane mask iteration) -----------------------
__device__ __forceinline__ float apply1(const u64* mi, const float* src){
  float a = 0.f;
  #pragma unroll
  for (int u = 0; u < 8; u++){
    u64 mm = mi[u];
    while (mm){ int l = __builtin_ctzll(mm); mm &= mm - 1; a += src[u * 64 + l]; }
  }
  return a;
}

__device__ __forceinline__ void apply7(const u64* mi, const float (*src)[NDIM],
                                       float* dst){
  #pragma unroll
  for (int f = 0; f < FIN; f++) dst[f] = 0.f;
  #pragma unroll
  for (int u = 0; u < 8; u++){
    u64 mm = mi[u];
    while (mm){
      int l = __builtin_ctzll(mm); mm &= mm - 1;
      int k = u * 64 + l;
      #pragma unroll
      for (int f = 0; f < FIN; f++) dst[f] += src[f][k];
    }
  }
}

// ---- fused per-graph: deg chain, d, s2, h (in regs), score, top-k, xp -----
__global__ __launch_bounds__(512) void score_kernel(
    const u64* __restrict__ maskT, const float* __restrict__ x,
    const float* __restrict__ panw, const float* __restrict__ w1,
    const float* __restrict__ b1, const float* __restrict__ pvec,
    const float* __restrict__ beta,
    float* __restrict__ dvec, int* __restrict__ idxOut,
    float* __restrict__ valOut, float* __restrict__ xp)
{
  const int g = blockIdx.x, t = threadIdx.x;     // t in [0,512)
  __shared__ float sA[NDIM], sB[NDIM], dl[NDIM], sv[NDIM];
  __shared__ float z[FIN][NDIM], zb[FIN][NDIM];
  __shared__ float W1s[FIN * HID];
  __shared__ float ps[HID];

  u64 mi[8];
  {
    const u64* mrow = maskT + (size_t)g * 8 * NDIM + t;
    #pragma unroll
    for (int u = 0; u < 8; u++) mi[u] = mrow[(size_t)u * NDIM];
  }
  if (t < FIN * HID) W1s[t] = w1[t];
  if (t < HID) ps[t] = pvec[t];

  const float w0 = panw[0], ww1 = panw[1], ww2 = panw[2], ww3 = panw[3];
  const float c0 = w0, c1 = c0 * ww1, c2 = c1 * ww2, c3 = c2 * ww3;

  // deg chain: d1 = A·1, d2 = A·d1, d3 = A·d2 (exact integers)
  int cdeg = 0;
  #pragma unroll
  for (int u = 0; u < 8; u++) cdeg += (int)__popcll(mi[u]);
  const float d1 = (float)cdeg;
  sA[t] = d1;
  __syncthreads();
  const float d2 = apply1(mi, sA);
  sB[t] = d2;
  __syncthreads();
  const float d3 = apply1(mi, sB);
  const float rs = c0 + c1 * d1 + c2 * d2 + c3 * d3;
  const float dd = rsqrtf(fmaxf(rs, 1.0f));
  dl[t] = dd;
  dvec[g * NDIM + t] = dd;
  __syncthreads();
  // s2 = d ∘ (M d)
  const float e1 = apply1(mi, dl);
  __syncthreads();
  sA[t] = e1;
  __syncthreads();
  const float e2 = apply1(mi, sA);
  __syncthreads();
  sB[t] = e2;
  __syncthreads();
  const float e3 = apply1(mi, sB);
  const float s2v = dd * (c0 * dd + c1 * e1 + c2 * e2 + c3 * e3);

  // z = d ∘ x ; y = c0 z + c1 Az + c2 A²z + c3 A³z
  float y[FIN];
  #pragma unroll
  for (int f = 0; f < FIN; f++){
    float zv = dd * x[((size_t)g * NDIM + t) * FIN + f];
    z[f][t] = zv;
    y[f] = c0 * zv;
  }
  __syncthreads();
  float w[FIN];
  apply7(mi, z, w);
  #pragma unroll
  for (int f = 0; f < FIN; f++){ y[f] += c1 * w[f]; zb[f][t] = w[f]; }
  __syncthreads();
  apply7(mi, zb, w);
  #pragma unroll
  for (int f = 0; f < FIN; f++) y[f] += c2 * w[f];
  __syncthreads();                     // all zb reads done; safe to reuse z
  #pragma unroll
  for (int f = 0; f < FIN; f++) z[f][t] = w[f];
  __syncthreads();
  apply7(mi, z, w);
  #pragma unroll
  for (int f = 0; f < FIN; f++) y[f] += c3 * w[f];

  // h row in registers; s1 = <h, p>
  float yin[FIN];
  #pragma unroll
  for (int f = 0; f < FIN; f++) yin[f] = dd * y[f];
  float hv[HID];
  float s1 = 0.f;
  #pragma unroll
  for (int o = 0; o < HID; o++){
    float zz = b1[o];
    #pragma unroll
    for (int f = 0; f < FIN; f++) zz = fmaf(yin[f], W1s[f * HID + o], zz);
    hv[o] = fmaxf(zz, 0.f);
    s1 = fmaf(hv[o], ps[o], s1);
  }
  const float sc = tanhf(beta[0] * s1 + beta[1] * s2v);
  sv[t] = sc;
  __syncthreads();
  // rank selection (val desc, idx asc)
  int rank = 0;
  #pragma unroll 8
  for (int j = 0; j < NDIM; j++){
    float u_ = sv[j];
    rank += (u_ > sc || (u_ == sc && j < t)) ? 1 : 0;
  }
  if (rank < KPOOL){
    idxOut[g * KPOOL + rank] = t;
    valOut[g * KPOOL + rank] = sc;
    float* xr = xp + ((size_t)g * KPOOL + rank) * HID;
    #pragma unroll
    for (int o = 0; o < HID; o++) xr[o] = hv[o] * sc;
  }
}

// ---- pooled adjacency v2: Apool = Mn[idx,idx] + I, di ---------------------
// A3 symmetric: A3pool[r][c] = sum_{k in N(ic)} A2[ir][k] — row-major A2 read.
// grid G*8 blocks, 8 waves/block, wave owns 2 pooled rows; column masks in
// REGISTERS (lane owns cols 2*lane, 2*lane+1); A2 rows staged coalesced.
__global__ __launch_bounds__(512) void pool_kernel(
    const u64* __restrict__ maskT, const unsigned char* __restrict__ A2u8,
    const int* __restrict__ idx, const float* __restrict__ dvec,
    const float* __restrict__ panw,
    float* __restrict__ Apool, float* __restrict__ di)
{
  const int b = blockIdx.x;
  const int g = b >> 3, rowgrp = b & 7;
  const int tid = threadIdx.x, w = tid >> 6, lane = tid & 63;
  __shared__ int idxs[KPOOL];
  __shared__ float dp[KPOOL];
  __shared__ unsigned char arow[16][NDIM];       // 8 KB: this block's A2 rows
  if (tid < KPOOL){
    int ia = idx[g * KPOOL + tid];
    idxs[tid] = ia;
    dp[tid] = dvec[g * NDIM + ia];
  }
  __syncthreads();
  const unsigned char* A2g = A2u8 + (size_t)g * NDIM * NDIM;
  // stage 16 A2 rows, coalesced (each wave: its 2 rows, 8 B/lane)
  #pragma unroll
  for (int e = 0; e < 2; e++){
    int j = w * 2 + e;
    int ir = idxs[rowgrp * 16 + j];
    *(uint2*)&arow[j][lane * 8] =
        *(const uint2*)(A2g + (size_t)ir * NDIM + lane * 8);
  }
  // column masks for this lane's 2 columns -> registers
  const int c0i = lane * 2, c1i = lane * 2 + 1;
  const int ic0 = idxs[c0i], ic1 = idxs[c1i];
  u64 cm0[8], cm1[8];
  {
    const u64* mg = maskT + (size_t)g * 8 * NDIM;
    #pragma unroll
    for (int u = 0; u < 8; u++){
      cm0[u] = mg[(size_t)u * NDIM + ic0];
      cm1[u] = mg[(size_t)u * NDIM + ic1];
    }
  }
  __syncthreads();
  const float w0 = panw[0], ww1 = panw[1], ww2 = panw[2], ww3 = panw[3];
  const float cc0 = w0, cc1 = cc0 * ww1, cc2 = cc1 * ww2, cc3 = cc2 * ww3;
  const float dc0 = dp[c0i], dc1 = dp[c1i];

  #pragma unroll
  for (int e = 0; e < 2; e++){
    const int j = w * 2 + e;
    const int r = rowgrp * 16 + j;
    const int ir = idxs[r];
    const float dpr = dp[r];
    const unsigned char* aj = arow[j];
    float a30 = 0.f, a31 = 0.f;
    #pragma unroll
    for (int u = 0; u < 8; u++){
      u64 m0 = cm0[u];
      while (m0){ int l = __builtin_ctzll(m0); m0 &= m0 - 1; a30 += (float)aj[u * 64 + l]; }
      u64 m1 = cm1[u];
      while (m1){ int l = __builtin_ctzll(m1); m1 &= m1 - 1; a31 += (float)aj[u * 64 + l]; }
    }
    float ab0 = (float)((cm0[ir >> 6] >> (ir & 63)) & 1ull);
    float ab1 = (float)((cm1[ir >> 6] >> (ir & 63)) & 1ull);
    float m0 = fmaf(cc3, a30, fmaf(cc2, (float)aj[ic0], cc1 * ab0));
    float m1 = fmaf(cc3, a31, fmaf(cc2, (float)aj[ic1], cc1 * ab1));
    if (r == c0i) m0 += cc0;
    if (r == c1i) m1 += cc0;
    float v0 = m0 * dpr * dc0;
    float v1 = m1 * dpr * dc1;
    if (r == c0i) v0 += 1.0f;
    if (r == c1i) v1 += 1.0f;
    float2 vv = make_float2(v0, v1);
    *(float2*)&Apool[((size_t)g * KPOOL + r) * KPOOL + c0i] = vv;
    float s = wred64(v0 + v1);
    if (lane == 0) di[g * KPOOL + r] = s > 0.f ? rsqrtf(s) : 0.f;
  }
}

// ---------------- pooled GCN: h2 = relu((An xp) W + b) ---------------------
__global__ __launch_bounds__(256) void gcn_kernel(
    const float* __restrict__ Apool, const float* __restrict__ di,
    const float* __restrict__ xp, const float* __restrict__ gw,
    const float* __restrict__ gb, float* __restrict__ h2)
{
  const int wid = threadIdx.x >> 6, lane = threadIdx.x & 63;
  const int row = blockIdx.x * 4 + wid;
  const int g = row >> 7, r = row & 127;
  const float dir = di[g * KPOOL + r];
  float acc = 0.f;
  for (int b = 0; b < KPOOL; b++){
    float an = Apool[(size_t)row * KPOOL + b] * dir * di[g * KPOOL + b];
    acc = fmaf(an, xp[((size_t)g * KPOOL + b) * HID + lane], acc);
  }
  __shared__ float ts[4][HID];
  ts[wid][lane] = acc;
  __syncthreads();
  float z = gb[lane];
  for (int f = 0; f < HID; f++) z = fmaf(ts[wid][f], gw[f * HID + lane], z);
  h2[(size_t)row * HID + lane] = fmaxf(z, 0.f);
}

// ---------------- head: pooled sum + linear + log_softmax ------------------
__global__ void head_kernel(const float* __restrict__ h2,
                            const float* __restrict__ lw,
                            const float* __restrict__ lb,
                            float* __restrict__ out)
{
  const int g = blockIdx.x;
  const int lane = threadIdx.x;
  float p = 0.f;
  for (int k = 0; k < KPOOL; k++) p += h2[((size_t)g * KPOOL + k) * HID + lane];
  float z0 = p * lw[lane * CLS + 0];
  float z1 = p * lw[lane * CLS + 1];
  z0 = wred64(z0);
  z1 = wred64(z1);
  if (lane == 0){
    float l0 = z0 + lb[0], l1 = z1 + lb[1];
    float m = fmaxf(l0, l1);
    float lse = m + logf(expf(l0 - m) + expf(l1 - m));
    out[g * CLS + 0] = l0 - lse;
    out[g * CLS + 1] = l1 - lse;
  }
}

extern "C" void kernel_launch(void* const* d_in, const int* in_sizes, int n_in,
                              void* d_out, int out_size, void* d_ws, size_t ws_size,
                              hipStream_t stream)
{
  const float* x    = (const float*)d_in[0];
  const float* adj  = (const float*)d_in[1];
  const float* panw = (const float*)d_in[2];
  const float* w1   = (const float*)d_in[3];
  const float* b1   = (const float*)d_in[4];
  const float* pvec = (const float*)d_in[5];
  const float* beta = (const float*)d_in[6];
  const float* gw   = (const float*)d_in[7];
  const float* gbv  = (const float*)d_in[8];
  const float* lw   = (const float*)d_in[9];
  const float* lb   = (const float*)d_in[10];
  float* out = (float*)d_out;

  char* ws = (char*)d_ws;
  u64* maskT = (u64*)ws;                                    // 2 MB
  unsigned char* A2u8 = (unsigned char*)(ws + (1 << 21));   // 16.8 MB
  char* p = ws + (1 << 21) + 16777216;
  float* dvec  = (float*)p;                       p += (size_t)G * NDIM * 4;
  int*   idx   = (int*)p;                         p += (size_t)G * KPOOL * 4;
  float* vals  = (float*)p;                       p += (size_t)G * KPOOL * 4;
  float* di    = (float*)p;                       p += (size_t)G * KPOOL * 4;
  float* xp    = (float*)p;                       p += (size_t)G * KPOOL * HID * 4;
  float* Apool = (float*)p;                       p += (size_t)G * KPOOL * KPOOL * 4;
  float* h2    = (float*)p;

  mask_kernel<<<G * NDIM / 4, 256, 0, stream>>>(adj, maskT);
  a2_kernel<<<512, 256, 0, stream>>>(maskT, A2u8);
  score_kernel<<<G, 512, 0, stream>>>(maskT, x, panw, w1, b1, pvec, beta,
                                      dvec, idx, vals, xp);
  pool_kernel<<<G * 8, 512, 0, stream>>>(maskT, A2u8, idx, dvec, panw, Apool, di);
  gcn_kernel<<<G * KPOOL / 4, 256, 0, stream>>>(Apool, di, xp, gw, gbv, h2);
  head_kernel<<<G, 64, 0, stream>>>(h2, lw, lb, out);
}